// Round 1
// baseline (310.536 us; speedup 1.0000x reference)
//
#include <hip/hip_runtime.h>
#include <cmath>

#define WS 11

struct GaussW { float g[WS]; };

__global__ __launch_bounds__(128) void ssim_row_kernel(
    const float* __restrict__ pred, const float* __restrict__ targ,
    GaussW gw, double* __restrict__ sum_ws)
{
    // Row layout: (B=16, C=3, H=512) rows of W=512 contiguous floats.
    __shared__ __align__(16) float sp[528];
    __shared__ __align__(16) float st[528];
    const int t = threadIdx.x;
    const long long row = blockIdx.x;            // 0 .. 24575
    const float* prow = pred + row * 512;
    const float* trow = targ + row * 512;

    // zero the W-padding halos: data lives at [8, 520), taps reach [3, 525)
    if (t < 8) {
        sp[t] = 0.f; st[t] = 0.f;
        sp[520 + t] = 0.f; st[520 + t] = 0.f;
    }
    // cooperative row load, 4 floats/thread, 16B-aligned LDS stores
    float4 p4 = *reinterpret_cast<const float4*>(prow + 4 * t);
    float4 t4 = *reinterpret_cast<const float4*>(trow + 4 * t);
    *reinterpret_cast<float4*>(&sp[8 + 4 * t]) = p4;
    *reinterpret_cast<float4*>(&st[8 + 4 * t]) = t4;
    __syncthreads();

    // Each thread owns 4 adjacent pixels w0..w0+3, w0 = 4t.
    // Taps for pixel w are sp[3+w .. 13+w]; for 4 pixels: 14 values.
    const int base = 3 + 4 * t;
    float p[14], q[14], pp[14], qq[14], pq[14];
    #pragma unroll
    for (int i = 0; i < 14; ++i) {
        p[i] = sp[base + i];
        q[i] = st[base + i];
        pp[i] = p[i] * p[i];
        qq[i] = q[i] * q[i];
        pq[i] = p[i] * q[i];
    }

    const float C1 = 0.0001f;   // 0.01^2
    const float C2 = 0.0009f;   // 0.03^2
    float acc = 0.f;
    #pragma unroll
    for (int px = 0; px < 4; ++px) {
        float mu1 = 0.f, mu2 = 0.f, m11 = 0.f, m22 = 0.f, m12 = 0.f;
        #pragma unroll
        for (int k = 0; k < WS; ++k) {
            const float g = gw.g[k];
            mu1 = fmaf(g, p[px + k], mu1);
            mu2 = fmaf(g, q[px + k], mu2);
            m11 = fmaf(g, pp[px + k], m11);
            m22 = fmaf(g, qq[px + k], m22);
            m12 = fmaf(g, pq[px + k], m12);
        }
        const float mu1sq = mu1 * mu1, mu2sq = mu2 * mu2, mu12 = mu1 * mu2;
        const float s1 = m11 - mu1sq, s2 = m22 - mu2sq, s12 = m12 - mu12;
        const float num = (2.f * mu12 + C1) * (2.f * s12 + C2);
        const float den = (mu1sq + mu2sq + C1) * (s1 + s2 + C2);
        acc += num / den;
    }

    // wave (64-lane) shuffle reduction, then 2-wave combine, 1 atomic/block
    #pragma unroll
    for (int off = 32; off > 0; off >>= 1)
        acc += __shfl_down(acc, off);
    __shared__ float wsum[2];
    const int wave = t >> 6, lane = t & 63;
    if (lane == 0) wsum[wave] = acc;
    __syncthreads();
    if (t == 0)
        atomicAdd(sum_ws, (double)(wsum[0] + wsum[1]));
}

__global__ void ssim_final_kernel(const double* __restrict__ sum_ws,
                                  float* __restrict__ out)
{
    // 10 zero-conv pad rows per (b,c) contribute ssim = 1 exactly:
    // 16*3*10*512 = 245760 elements; total = 16*3*522*512 = 12828672.
    const double s = sum_ws[0] + 245760.0;
    out[0] = (float)(1.0 - s / 12828672.0);
}

extern "C" void kernel_launch(void* const* d_in, const int* in_sizes, int n_in,
                              void* d_out, int out_size, void* d_ws, size_t ws_size,
                              hipStream_t stream) {
    const float* pred = (const float*)d_in[0];
    const float* targ = (const float*)d_in[1];
    float* out = (float*)d_out;
    double* sum_ws = (double*)d_ws;

    // Gaussian window, computed exactly as the reference (sigma=1.5, ws=11).
    GaussW gw;
    double graw[WS], s = 0.0;
    for (int i = 0; i < WS; ++i) {
        const double c = (double)(i - WS / 2);
        graw[i] = exp(-c * c / (2.0 * 1.5 * 1.5));
        s += graw[i];
    }
    for (int i = 0; i < WS; ++i) gw.g[i] = (float)(graw[i] / s);

    hipMemsetAsync(d_ws, 0, sizeof(double), stream);

    const int rows = 16 * 3 * 512;   // 24576
    ssim_row_kernel<<<rows, 128, 0, stream>>>(pred, targ, gw, sum_ws);
    ssim_final_kernel<<<1, 1, 0, stream>>>(sum_ws, out);
}

// Round 2
// 37.868 us; speedup vs baseline: 8.2006x; 8.2006x over previous
//
#include <hip/hip_runtime.h>
#include <cmath>

#define WS 11

struct GaussW { float g[WS]; };

// 16*3*512 = 24576 rows of 512 floats. One wave (64 lanes) per row,
// 8 pixels per lane. 2048 blocks x 4 waves x 3 rows/wave.
__global__ __launch_bounds__(256) void ssim_row_kernel(
    const float* __restrict__ pred, const float* __restrict__ targ,
    GaussW gw, float* __restrict__ partials)
{
    const int t = threadIdx.x;
    const int lane = t & 63;
    const int wave = t >> 6;
    const int wave_id = blockIdx.x * 4 + wave;   // 0..8191
    const float C1 = 0.0001f, C2 = 0.0009f;

    float acc = 0.f;
    #pragma unroll
    for (int r = 0; r < 3; ++r) {
        const long long row = (long long)wave_id + 8192LL * r;   // 0..24575
        const float* prow = pred + row * 512 + 8 * lane;
        const float* trow = targ + row * 512 + 8 * lane;

        // taps a[0..17] / b[0..17] cover row pixels [8*lane-5, 8*lane+12]
        float a[18], b[18];
        {
            float4 p0 = *reinterpret_cast<const float4*>(prow);
            float4 p1 = *reinterpret_cast<const float4*>(prow + 4);
            float4 q0 = *reinterpret_cast<const float4*>(trow);
            float4 q1 = *reinterpret_cast<const float4*>(trow + 4);
            a[5] = p0.x; a[6] = p0.y; a[7] = p0.z; a[8] = p0.w;
            a[9] = p1.x; a[10] = p1.y; a[11] = p1.z; a[12] = p1.w;
            b[5] = q0.x; b[6] = q0.y; b[7] = q0.z; b[8] = q0.w;
            b[9] = q1.x; b[10] = q1.y; b[11] = q1.z; b[12] = q1.w;
        }
        // halos from neighbor lanes; zero at row edges (the W zero-padding)
        #pragma unroll
        for (int i = 0; i < 5; ++i) {
            float la = __shfl_up(a[8 + i], 1);    // lane-1 floats 3..7
            float lb = __shfl_up(b[8 + i], 1);
            float ra = __shfl_down(a[5 + i], 1);  // lane+1 floats 0..4
            float rb = __shfl_down(b[5 + i], 1);
            a[i]      = (lane == 0)  ? 0.f : la;
            b[i]      = (lane == 0)  ? 0.f : lb;
            a[13 + i] = (lane == 63) ? 0.f : ra;
            b[13 + i] = (lane == 63) ? 0.f : rb;
        }

        #pragma unroll
        for (int px = 0; px < 8; ++px) {
            float mu1 = 0.f, mu2 = 0.f, m11 = 0.f, m22 = 0.f, m12 = 0.f;
            #pragma unroll
            for (int k = 0; k < WS; ++k) {
                const float g  = gw.g[k];
                const float pk = a[px + k];
                const float qk = b[px + k];
                mu1 = fmaf(g, pk, mu1);
                mu2 = fmaf(g, qk, mu2);
                const float gp = g * pk;
                const float gq = g * qk;
                m11 = fmaf(gp, pk, m11);
                m12 = fmaf(gp, qk, m12);
                m22 = fmaf(gq, qk, m22);
            }
            const float mu1sq = mu1 * mu1, mu2sq = mu2 * mu2, mu12 = mu1 * mu2;
            const float s1 = m11 - mu1sq, s2 = m22 - mu2sq, s12 = m12 - mu12;
            const float num = fmaf(2.f, mu12, C1) * fmaf(2.f, s12, C2);
            const float den = (mu1sq + mu2sq + C1) * (s1 + s2 + C2);
            acc = fmaf(num, __builtin_amdgcn_rcpf(den), acc);
        }
    }

    // wave reduction
    #pragma unroll
    for (int off = 32; off > 0; off >>= 1)
        acc += __shfl_down(acc, off);
    __shared__ float wsum[4];
    if (lane == 0) wsum[wave] = acc;
    __syncthreads();
    if (t == 0)
        partials[blockIdx.x] = wsum[0] + wsum[1] + wsum[2] + wsum[3];
}

// Sum 2048 block partials in double; add the 10 zero-pad rows per (b,c)
// which contribute ssim == 1 exactly: 16*3*10*512 = 245760 elements.
// Total elements: 16*3*522*512 = 12828672.
__global__ __launch_bounds__(256) void ssim_final_kernel(
    const float* __restrict__ partials, float* __restrict__ out)
{
    const int t = threadIdx.x;
    double d = 0.0;
    #pragma unroll
    for (int i = 0; i < 8; ++i)
        d += (double)partials[t + 256 * i];
    #pragma unroll
    for (int off = 32; off > 0; off >>= 1)
        d += __shfl_down(d, off);
    __shared__ double wsumd[4];
    const int lane = t & 63, wave = t >> 6;
    if (lane == 0) wsumd[wave] = d;
    __syncthreads();
    if (t == 0) {
        const double s = wsumd[0] + wsumd[1] + wsumd[2] + wsumd[3] + 245760.0;
        out[0] = (float)(1.0 - s / 12828672.0);
    }
}

extern "C" void kernel_launch(void* const* d_in, const int* in_sizes, int n_in,
                              void* d_out, int out_size, void* d_ws, size_t ws_size,
                              hipStream_t stream) {
    const float* pred = (const float*)d_in[0];
    const float* targ = (const float*)d_in[1];
    float* out = (float*)d_out;
    float* partials = (float*)d_ws;   // 2048 floats

    // Gaussian window, exactly as the reference (sigma=1.5, ws=11).
    GaussW gw;
    double graw[WS], s = 0.0;
    for (int i = 0; i < WS; ++i) {
        const double c = (double)(i - WS / 2);
        graw[i] = exp(-c * c / (2.0 * 1.5 * 1.5));
        s += graw[i];
    }
    for (int i = 0; i < WS; ++i) gw.g[i] = (float)(graw[i] / s);

    ssim_row_kernel<<<2048, 256, 0, stream>>>(pred, targ, gw, partials);
    ssim_final_kernel<<<1, 256, 0, stream>>>(partials, out);
}

// Round 3
// 30.446 us; speedup vs baseline: 10.1995x; 1.2438x over previous
//
#include <hip/hip_runtime.h>
#include <cmath>

#define WS 11

struct GaussW { float g[WS]; };

// 16*3*512 = 24576 rows of 512 floats. One wave (64 lanes) per row,
// 8 pixels per lane, 3 rows per wave, prefetch next row during compute.
// 4-conv identity: u=p+q, v=p-q; conv(u),conv(v),conv(u^2),conv(v^2)
// recover all five SSIM moments.
__global__ __launch_bounds__(256) void ssim_row_kernel(
    const float* __restrict__ pred, const float* __restrict__ targ,
    GaussW gw, float* __restrict__ partials)
{
    const int t = threadIdx.x;
    const int lane = t & 63;
    const int wave = t >> 6;
    const int wave_id = blockIdx.x * 4 + wave;   // 0..8191
    const float C1 = 0.0001f, C2 = 0.0009f;

    const long long off = (long long)wave_id * 512 + 8 * lane;
    const float* prow = pred + off;
    const float* trow = targ + off;

    float4 P0 = *reinterpret_cast<const float4*>(prow);
    float4 P1 = *reinterpret_cast<const float4*>(prow + 4);
    float4 Q0 = *reinterpret_cast<const float4*>(trow);
    float4 Q1 = *reinterpret_cast<const float4*>(trow + 4);

    float acc = 0.f;
    #pragma unroll
    for (int r = 0; r < 3; ++r) {
        // prefetch next row (8192 rows apart) before computing this one
        float4 nP0, nP1, nQ0, nQ1;
        if (r < 2) {
            const float* pn = prow + (long long)(r + 1) * 8192 * 512;
            const float* tn = trow + (long long)(r + 1) * 8192 * 512;
            nP0 = *reinterpret_cast<const float4*>(pn);
            nP1 = *reinterpret_cast<const float4*>(pn + 4);
            nQ0 = *reinterpret_cast<const float4*>(tn);
            nQ1 = *reinterpret_cast<const float4*>(tn + 4);
        }

        // u,v taps 0..17 cover row pixels [8*lane-5, 8*lane+12]
        float u[18], v[18], su[18], sv[18];
        {
            const float pv[8] = {P0.x, P0.y, P0.z, P0.w, P1.x, P1.y, P1.z, P1.w};
            const float qv[8] = {Q0.x, Q0.y, Q0.z, Q0.w, Q1.x, Q1.y, Q1.z, Q1.w};
            #pragma unroll
            for (int i = 0; i < 8; ++i) {
                u[5 + i] = pv[i] + qv[i];
                v[5 + i] = pv[i] - qv[i];
            }
        }
        // halos from neighbor lanes; zero at row edges (the W zero-padding)
        #pragma unroll
        for (int i = 0; i < 5; ++i) {
            float lu = __shfl_up(u[8 + i], 1);    // lane-1 pixels 3..7
            float lv = __shfl_up(v[8 + i], 1);
            float ru = __shfl_down(u[5 + i], 1);  // lane+1 pixels 0..4
            float rv = __shfl_down(v[5 + i], 1);
            u[i]      = (lane == 0)  ? 0.f : lu;
            v[i]      = (lane == 0)  ? 0.f : lv;
            u[13 + i] = (lane == 63) ? 0.f : ru;
            v[13 + i] = (lane == 63) ? 0.f : rv;
        }
        #pragma unroll
        for (int i = 0; i < 18; ++i) { su[i] = u[i] * u[i]; sv[i] = v[i] * v[i]; }

        #pragma unroll
        for (int px = 0; px < 8; ++px) {
            float A = 0.f, B = 0.f, SU = 0.f, SV = 0.f;
            #pragma unroll
            for (int k = 0; k < WS; ++k) {
                const float g = gw.g[k];
                A  = fmaf(g, u[px + k], A);
                B  = fmaf(g, v[px + k], B);
                SU = fmaf(g, su[px + k], SU);
                SV = fmaf(g, sv[px + k], SV);
            }
            // A=mu1+mu2, B=mu1-mu2, SU=m11+2m12+m22, SV=m11-2m12+m22
            const float a2 = A * A, b2 = B * B;
            const float d2 = a2 - b2;            // 4*mu1*mu2
            const float t2 = a2 + b2;            // 2*(mu1^2+mu2^2)
            const float num1 = fmaf(0.5f, d2, C1);        // 2*mu12+C1
            const float den1 = fmaf(0.5f, t2, C1);        // mu1^2+mu2^2+C1
            const float ds = SU - SV;            // 4*m12
            const float ts = SU + SV;            // 2*(m11+m22)
            const float num2 = fmaf(0.5f, ds - d2, C2);   // 2*s12+C2
            const float den2 = fmaf(0.5f, ts - t2, C2);   // s1+s2+C2
            acc = fmaf(num1 * num2, __builtin_amdgcn_rcpf(den1 * den2), acc);
        }

        if (r < 2) { P0 = nP0; P1 = nP1; Q0 = nQ0; Q1 = nQ1; }
    }

    // wave reduction, then block combine, partials (no atomics)
    #pragma unroll
    for (int offr = 32; offr > 0; offr >>= 1)
        acc += __shfl_down(acc, offr);
    __shared__ float wsum[4];
    if (lane == 0) wsum[wave] = acc;
    __syncthreads();
    if (t == 0)
        partials[blockIdx.x] = wsum[0] + wsum[1] + wsum[2] + wsum[3];
}

// Sum 2048 block partials in double; the 10 zero-pad rows per (b,c)
// contribute ssim == 1 exactly: 16*3*10*512 = 245760 elements.
// Total elements: 16*3*522*512 = 12828672.
__global__ __launch_bounds__(256) void ssim_final_kernel(
    const float* __restrict__ partials, float* __restrict__ out)
{
    const int t = threadIdx.x;
    double d = 0.0;
    #pragma unroll
    for (int i = 0; i < 8; ++i)
        d += (double)partials[t + 256 * i];
    #pragma unroll
    for (int offr = 32; offr > 0; offr >>= 1)
        d += __shfl_down(d, offr);
    __shared__ double wsumd[4];
    const int lane = t & 63, wave = t >> 6;
    if (lane == 0) wsumd[wave] = d;
    __syncthreads();
    if (t == 0) {
        const double s = wsumd[0] + wsumd[1] + wsumd[2] + wsumd[3] + 245760.0;
        out[0] = (float)(1.0 - s / 12828672.0);
    }
}

extern "C" void kernel_launch(void* const* d_in, const int* in_sizes, int n_in,
                              void* d_out, int out_size, void* d_ws, size_t ws_size,
                              hipStream_t stream) {
    const float* pred = (const float*)d_in[0];
    const float* targ = (const float*)d_in[1];
    float* out = (float*)d_out;
    float* partials = (float*)d_ws;   // 2048 floats

    // Gaussian window, exactly as the reference (sigma=1.5, ws=11).
    GaussW gw;
    double graw[WS], s = 0.0;
    for (int i = 0; i < WS; ++i) {
        const double c = (double)(i - WS / 2);
        graw[i] = exp(-c * c / (2.0 * 1.5 * 1.5));
        s += graw[i];
    }
    for (int i = 0; i < WS; ++i) gw.g[i] = (float)(graw[i] / s);

    ssim_row_kernel<<<2048, 256, 0, stream>>>(pred, targ, gw, partials);
    ssim_final_kernel<<<1, 256, 0, stream>>>(partials, out);
}

// Round 4
// 27.876 us; speedup vs baseline: 11.1399x; 1.0922x over previous
//
#include <hip/hip_runtime.h>
#include <cmath>

#define WS 11

typedef float v2f __attribute__((ext_vector_type(2)));

struct GaussW { float g[WS]; };

// 16*3*512 = 24576 rows of 512 floats. One wave (64 lanes) per row,
// 8 pixels per lane, 3 rows per wave, prefetch next row during compute.
// 4-conv identity: u=p+q, v=p-q; conv(u),conv(v),conv(u^2),conv(v^2)
// recover all five SSIM moments. (u,v) and (u^2,v^2) are packed as
// float2 so each conv tap is one v_pk_fma_f32 (dual-issue packed FP32).
__global__ __launch_bounds__(256) void ssim_row_kernel(
    const float* __restrict__ pred, const float* __restrict__ targ,
    GaussW gw, float* __restrict__ partials)
{
    const int t = threadIdx.x;
    const int lane = t & 63;
    const int wave = t >> 6;
    const int wave_id = blockIdx.x * 4 + wave;   // 0..8191
    const float C1 = 0.0001f, C2 = 0.0009f;

    const long long off = (long long)wave_id * 512 + 8 * lane;
    const float* prow = pred + off;
    const float* trow = targ + off;

    float4 P0 = *reinterpret_cast<const float4*>(prow);
    float4 P1 = *reinterpret_cast<const float4*>(prow + 4);
    float4 Q0 = *reinterpret_cast<const float4*>(trow);
    float4 Q1 = *reinterpret_cast<const float4*>(trow + 4);

    float acc = 0.f;
    #pragma unroll
    for (int r = 0; r < 3; ++r) {
        // prefetch next row (8192 rows apart) before computing this one
        float4 nP0, nP1, nQ0, nQ1;
        if (r < 2) {
            const float* pn = prow + (long long)(r + 1) * 8192 * 512;
            const float* tn = trow + (long long)(r + 1) * 8192 * 512;
            nP0 = *reinterpret_cast<const float4*>(pn);
            nP1 = *reinterpret_cast<const float4*>(pn + 4);
            nQ0 = *reinterpret_cast<const float4*>(tn);
            nQ1 = *reinterpret_cast<const float4*>(tn + 4);
        }

        // w[i] = (u,v), s[i] = (u^2,v^2); taps 0..17 cover pixels
        // [8*lane-5, 8*lane+12] of the row.
        v2f w[18], s[18];
        {
            const float pv[8] = {P0.x, P0.y, P0.z, P0.w, P1.x, P1.y, P1.z, P1.w};
            const float qv[8] = {Q0.x, Q0.y, Q0.z, Q0.w, Q1.x, Q1.y, Q1.z, Q1.w};
            #pragma unroll
            for (int i = 0; i < 8; ++i) {
                w[5 + i].x = pv[i] + qv[i];
                w[5 + i].y = pv[i] - qv[i];
            }
        }
        // halos from neighbor lanes; zero at row edges (the W zero-padding)
        #pragma unroll
        for (int i = 0; i < 5; ++i) {
            float lu = __shfl_up(w[8 + i].x, 1);    // lane-1 pixels 3..7
            float lv = __shfl_up(w[8 + i].y, 1);
            float ru = __shfl_down(w[5 + i].x, 1);  // lane+1 pixels 0..4
            float rv = __shfl_down(w[5 + i].y, 1);
            w[i].x      = (lane == 0)  ? 0.f : lu;
            w[i].y      = (lane == 0)  ? 0.f : lv;
            w[13 + i].x = (lane == 63) ? 0.f : ru;
            w[13 + i].y = (lane == 63) ? 0.f : rv;
        }
        #pragma unroll
        for (int i = 0; i < 18; ++i) s[i] = w[i] * w[i];

        #pragma unroll
        for (int px = 0; px < 8; ++px) {
            v2f AB  = {0.f, 0.f};   // (Σg·u, Σg·v)   = (mu1+mu2, mu1-mu2)
            v2f SUV = {0.f, 0.f};   // (Σg·u², Σg·v²)
            #pragma unroll
            for (int k = 0; k < WS; ++k) {
                const v2f g2 = {gw.g[k], gw.g[k]};
                AB  = __builtin_elementwise_fma(g2, w[px + k], AB);
                SUV = __builtin_elementwise_fma(g2, s[px + k], SUV);
            }
            const v2f ab2 = AB * AB;             // (A^2, B^2)
            const float d2 = ab2.x - ab2.y;      // 4*mu1*mu2
            const float t2 = ab2.x + ab2.y;      // 2*(mu1^2+mu2^2)
            const float ds = SUV.x - SUV.y;      // 4*m12
            const float ts = SUV.x + SUV.y;      // 2*(m11+m22)
            const float num1 = fmaf(0.5f, d2, C1);        // 2*mu12+C1
            const float den1 = fmaf(0.5f, t2, C1);        // mu1^2+mu2^2+C1
            const float num2 = fmaf(0.5f, ds - d2, C2);   // 2*s12+C2
            const float den2 = fmaf(0.5f, ts - t2, C2);   // s1+s2+C2
            acc = fmaf(num1 * num2, __builtin_amdgcn_rcpf(den1 * den2), acc);
        }

        if (r < 2) { P0 = nP0; P1 = nP1; Q0 = nQ0; Q1 = nQ1; }
    }

    // wave reduction, then block combine, partials (no atomics)
    #pragma unroll
    for (int offr = 32; offr > 0; offr >>= 1)
        acc += __shfl_down(acc, offr);
    __shared__ float wsum[4];
    if (lane == 0) wsum[wave] = acc;
    __syncthreads();
    if (t == 0)
        partials[blockIdx.x] = wsum[0] + wsum[1] + wsum[2] + wsum[3];
}

// Sum 2048 block partials in double; the 10 zero-pad rows per (b,c)
// contribute ssim == 1 exactly: 16*3*10*512 = 245760 elements.
// Total elements: 16*3*522*512 = 12828672.
__global__ __launch_bounds__(256) void ssim_final_kernel(
    const float* __restrict__ partials, float* __restrict__ out)
{
    const int t = threadIdx.x;
    double d = 0.0;
    #pragma unroll
    for (int i = 0; i < 8; ++i)
        d += (double)partials[t + 256 * i];
    #pragma unroll
    for (int offr = 32; offr > 0; offr >>= 1)
        d += __shfl_down(d, offr);
    __shared__ double wsumd[4];
    const int lane = t & 63, wave = t >> 6;
    if (lane == 0) wsumd[wave] = d;
    __syncthreads();
    if (t == 0) {
        const double s = wsumd[0] + wsumd[1] + wsumd[2] + wsumd[3] + 245760.0;
        out[0] = (float)(1.0 - s / 12828672.0);
    }
}

extern "C" void kernel_launch(void* const* d_in, const int* in_sizes, int n_in,
                              void* d_out, int out_size, void* d_ws, size_t ws_size,
                              hipStream_t stream) {
    const float* pred = (const float*)d_in[0];
    const float* targ = (const float*)d_in[1];
    float* out = (float*)d_out;
    float* partials = (float*)d_ws;   // 2048 floats

    // Gaussian window, exactly as the reference (sigma=1.5, ws=11).
    GaussW gw;
    double graw[WS], s = 0.0;
    for (int i = 0; i < WS; ++i) {
        const double c = (double)(i - WS / 2);
        graw[i] = exp(-c * c / (2.0 * 1.5 * 1.5));
        s += graw[i];
    }
    for (int i = 0; i < WS; ++i) gw.g[i] = (float)(graw[i] / s);

    ssim_row_kernel<<<2048, 256, 0, stream>>>(pred, targ, gw, partials);
    ssim_final_kernel<<<1, 256, 0, stream>>>(partials, out);
}